// Round 13
// baseline (44.708 us; speedup 1.0000x reference)
//
#include <hip/hip_runtime.h>
#include <math.h>

#define NN   96
#define NPOS (96*96)   // 9216
#define BB   32
#define KV   1024
#define KA   2048

// ws layout (float offsets) — identical to r12 so nbT pack is untouched
#define EXTV_OFF  0
#define EXTA_OFF  (BB*NPOS)            // 294912 (single audio buffer now)
#define EXTA1_OFF (2*BB*NPOS)          // unused, keeps offsets stable
#define CPT_OFF   (3*BB*NPOS)          // 884736
#define AFV_OFF   (CPT_OFF + 6*NPOS)   // 940032
#define AFV_SLOTS ((KV/32)*2*64)       // 4096 16B-slots
#define AFA_OFF   (AFV_OFF + AFV_SLOTS*4)  // 956416
#define AFA_SLOTS ((KA/32)*2*64)       // 8192

typedef __bf16 bf16x8 __attribute__((ext_vector_type(8)));
typedef __bf16 bf16x4 __attribute__((ext_vector_type(4)));
typedef float  f32x4  __attribute__((ext_vector_type(4)));

// ---------------- nb (separable DoG) + vid/aud -> bf16 A-fragment pack ----------------
__global__ __launch_bounds__(256) void nbT_kernel(
    const float* __restrict__ na_v, const float* __restrict__ na_a,
    const float* __restrict__ na_m, const float* __restrict__ video,
    const float* __restrict__ audio, float* __restrict__ ws)
{
    __shared__ float G[96][100];
    __shared__ float act_s[96][100];
    __shared__ float T1t[24][100];

    if (blockIdx.x >= 24) {
        // A-fragment pack: A[16x32] lane layout row=l&15, k=(l>>4)*8+j
        const int e = (blockIdx.x - 24) * 256 + threadIdx.x;   // 0..12287
        const float* src; bf16x8* dst; int K, el;
        if (e < AFV_SLOTS) { src = video; K = KV; dst = (bf16x8*)(ws + AFV_OFF); el = e; }
        else               { src = audio; K = KA; dst = (bf16x8*)(ws + AFA_OFF); el = e - AFV_SLOTS; }
        const int l  = el & 63;
        const int hb = (el >> 6) & 1;
        const int sg = el >> 7;
        const int b  = hb * 16 + (l & 15);
        const int k0 = sg * 32 + ((l >> 4) << 3);
        const float4 f0 = *(const float4*)&src[(size_t)b * K + k0];
        const float4 f1 = *(const float4*)&src[(size_t)b * K + k0 + 4];
        bf16x8 v;
        v[0] = (__bf16)f0.x; v[1] = (__bf16)f0.y; v[2] = (__bf16)f0.z; v[3] = (__bf16)f0.w;
        v[4] = (__bf16)f1.x; v[5] = (__bf16)f1.y; v[6] = (__bf16)f1.z; v[7] = (__bf16)f1.w;
        dst[el] = v;
        return;
    }

    const int c  = blockIdx.x >> 2;
    const int js = (blockIdx.x & 3) * 24;
    float l, s;
    if      (c == 0) { l =  1.60f; s = 3.5f;  }
    else if (c == 1) { l = -1.23f; s = 6.3f;  }
    else if (c == 2) { l =  1.00f; s = 5.3f;  }
    else if (c == 3) { l = -0.80f; s = 11.8f; }
    else if (c == 4) { l =  3.80f; s = 3.5f;  }
    else             { l = -3.30f; s = 6.2f;  }
    const float s2 = s * s;
    const int f = c >> 1;
    const float* act = (f == 0) ? na_v : (f == 1) ? na_a : na_m;
    const int tid = threadIdx.x;
    float* cpt = ws + CPT_OFF;

    for (int idx = tid; idx < 9216; idx += 256) {
        int j = idx / 96, k = idx - j * 96;
        int d = abs(j - k); d = min(d, 96 - d);
        G[j][k]     = __expf(-0.5f * (float)(d * d) * s2);
        act_s[j][k] = act[idx];
    }
    __syncthreads();

    const int hg3 = (tid >> 3) * 3;
    const int jl3 = (tid & 7) * 3;

    float t1[3][3] = {};
    for (int k0 = 0; k0 < 96; k0 += 4) {
        float4 av[3], gv[3];
        #pragma unroll
        for (int r = 0; r < 3; r++) {
            av[r] = *(const float4*)&act_s[hg3 + r][k0];
            gv[r] = *(const float4*)&G[js + jl3 + r][k0];
        }
        #pragma unroll
        for (int hh = 0; hh < 3; hh++)
            #pragma unroll
            for (int jj = 0; jj < 3; jj++)
                t1[hh][jj] += av[hh].x * gv[jj].x + av[hh].y * gv[jj].y
                            + av[hh].z * gv[jj].z + av[hh].w * gv[jj].w;
    }
    #pragma unroll
    for (int hh = 0; hh < 3; hh++)
        #pragma unroll
        for (int jj = 0; jj < 3; jj++)
            T1t[jl3 + jj][hg3 + hh] = t1[hh][jj];
    __syncthreads();

    float o[3][3] = {};
    for (int h0 = 0; h0 < 96; h0 += 4) {
        float4 gv[3], tv[3];
        #pragma unroll
        for (int r = 0; r < 3; r++) {
            gv[r] = *(const float4*)&G[hg3 + r][h0];
            tv[r] = *(const float4*)&T1t[jl3 + r][h0];
        }
        #pragma unroll
        for (int ii = 0; ii < 3; ii++)
            #pragma unroll
            for (int jj = 0; jj < 3; jj++)
                o[ii][jj] += gv[ii].x * tv[jj].x + gv[ii].y * tv[jj].y
                           + gv[ii].z * tv[jj].z + gv[ii].w * tv[jj].w;
    }
    #pragma unroll
    for (int ii = 0; ii < 3; ii++)
        #pragma unroll
        for (int jj = 0; jj < 3; jj++)
            cpt[c * NPOS + (hg3 + ii) * 96 + (js + jl3 + jj)] = l * o[ii][jj];
}

// ---------------- ext GEMM: 6-subtile software pipeline, continuous rf stream ----
// Block = 16 pos, 512 thr, walks 6 subtiles (audio k 0..2047 in 4, video in 2).
// Iter s: C(s) computes from buf[s&1] while S(s+1) (4x 1KB dense loads, issued
// last iter) is in flight; af(s+1) issued BEFORE S(s+2) so in-order vmcnt
// retirement never drains the stage stream. Raw s_barrier + lgkmcnt(0) only
// (no __syncthreads -> no vmcnt(0) drain). One barrier per subtile.
#define LROW 1040
#define BUFSZ (16*LROW)      // 16640
#define REDOFF (2*BUFSZ)     // 33280
__global__ __launch_bounds__(512, 4) void ext_mfma(
    const float* __restrict__ rf_v, const float* __restrict__ rf_a,
    float* __restrict__ ws)
{
    __shared__ char lds[2 * BUFSZ + 6144];   // 39424 B
    const int tid = threadIdx.x;
    const int pt  = blockIdx.x;              // 0..575
    const int p0  = pt * 16;

    // stage lanes: row r = tid>>7 (rows r,r+4,r+8,r+12), 16B col c128 = tid&127
    const int r    = tid >> 7;
    const int c128 = tid & 127;
    // compute lanes
    const int l  = tid & 63, w = tid >> 6;
    const int bh = w & 1, kq = w >> 1;       // batch-half, k-quarter
    const int rb_off = (l & 15) * LROW + kq * 256 + ((l >> 4) << 4);

    // per-subtile stage sources (thread-offset included) and af bases
    const float*  sb[6];
    const bf16x8* ab[6];
    {
        const float* ra = rf_a + (size_t)(p0 + r) * KA + c128 * 4;
        const float* rv = rf_v + (size_t)(p0 + r) * KV + c128 * 4;
        sb[0] = ra;        sb[1] = ra + 512;
        sb[2] = ra + 1024; sb[3] = ra + 1536;
        sb[4] = rv;        sb[5] = rv + 512;
        const bf16x8* aa = (const bf16x8*)(ws + AFA_OFF) + kq * 4 * 128 + (bh << 6) + l;
        const bf16x8* av = (const bf16x8*)(ws + AFV_OFF) + kq * 4 * 128 + (bh << 6) + l;
        ab[0] = aa;        ab[1] = aa + 16 * 128;
        ab[2] = aa + 32 * 128; ab[3] = aa + 48 * 128;
        ab[4] = av;        ab[5] = av + 16 * 128;
    }

    float4 fa0, fa1, fa2, fa3;
    bf16x8 xA0, xA1, xA2, xA3, xB0, xB1, xB2, xB3;
    f32x4 accA = {0.f, 0.f, 0.f, 0.f};
    f32x4 accV = {0.f, 0.f, 0.f, 0.f};

#define STAGE(S, KK) do {                                         \
        fa0 = *(const float4*)(sb[S]);                            \
        fa1 = *(const float4*)(sb[S] + 4  * (size_t)(KK));        \
        fa2 = *(const float4*)(sb[S] + 8  * (size_t)(KK));        \
        fa3 = *(const float4*)(sb[S] + 12 * (size_t)(KK));        \
    } while (0)

#define CVT4(F) ({ bf16x4 v_;                                     \
        v_[0] = (__bf16)(F).x; v_[1] = (__bf16)(F).y;             \
        v_[2] = (__bf16)(F).z; v_[3] = (__bf16)(F).w; v_; })

#define WWRITE(S) do {                                            \
        char* bw = lds + ((S) & 1) * BUFSZ + c128 * 8;            \
        *(bf16x4*)(bw + (r +  0) * LROW) = CVT4(fa0);             \
        *(bf16x4*)(bw + (r +  4) * LROW) = CVT4(fa1);             \
        *(bf16x4*)(bw + (r +  8) * LROW) = CVT4(fa2);             \
        *(bf16x4*)(bw + (r + 12) * LROW) = CVT4(fa3);             \
    } while (0)

#define AFLD(S, A0, A1, A2, A3) do {                              \
        const bf16x8* ap_ = ab[S];                                \
        A0 = ap_[0]; A1 = ap_[128]; A2 = ap_[256]; A3 = ap_[384]; \
    } while (0)

#define COMP(S, ACC, A0, A1, A2, A3) do {                                      \
        const char* br = lds + ((S) & 1) * BUFSZ + rb_off;                     \
        bf16x8 b0 = *(const bf16x8*)(br);                                      \
        bf16x8 b1 = *(const bf16x8*)(br + 64);                                 \
        bf16x8 b2 = *(const bf16x8*)(br + 128);                                \
        bf16x8 b3 = *(const bf16x8*)(br + 192);                                \
        ACC = __builtin_amdgcn_mfma_f32_16x16x32_bf16(A0, b0, ACC, 0, 0, 0);   \
        ACC = __builtin_amdgcn_mfma_f32_16x16x32_bf16(A1, b1, ACC, 0, 0, 0);   \
        ACC = __builtin_amdgcn_mfma_f32_16x16x32_bf16(A2, b2, ACC, 0, 0, 0);   \
        ACC = __builtin_amdgcn_mfma_f32_16x16x32_bf16(A3, b3, ACC, 0, 0, 0);   \
    } while (0)

#define BARL do {                                                 \
        asm volatile("s_waitcnt lgkmcnt(0)" ::: "memory");        \
        __builtin_amdgcn_sched_barrier(0);                        \
        __builtin_amdgcn_s_barrier();                             \
        __builtin_amdgcn_sched_barrier(0);                        \
    } while (0)

#define REDUCE(ACC, EXTP) do {                                                 \
        if (kq) *(f32x4*)(lds + REDOFF + (((kq - 1) << 1) + bh) * 1024         \
                          + l * 16) = ACC;                                     \
        BARL;                                                                  \
        if (!kq) {                                                             \
            ACC += *(const f32x4*)(lds + REDOFF + (0 * 2 + bh) * 1024 + l*16); \
            ACC += *(const f32x4*)(lds + REDOFF + (1 * 2 + bh) * 1024 + l*16); \
            ACC += *(const f32x4*)(lds + REDOFF + (2 * 2 + bh) * 1024 + l*16); \
            const int pcol = p0 + (l & 15);                                    \
            const int br0  = (bh << 4) + ((l >> 4) << 2);                      \
            float* ep = (EXTP);                                                \
            ep[(size_t)(br0 + 0) * NPOS + pcol] = ACC[0];                      \
            ep[(size_t)(br0 + 1) * NPOS + pcol] = ACC[1];                      \
            ep[(size_t)(br0 + 2) * NPOS + pcol] = ACC[2];                      \
            ep[(size_t)(br0 + 3) * NPOS + pcol] = ACC[3];                      \
        }                                                                      \
    } while (0)

    // prologue: S0; af0; W0 (waits S0, af0 stays out); S1; barrier
    STAGE(0, KA); AFLD(0, xA0, xA1, xA2, xA3);
    WWRITE(0);
    STAGE(1, KA);
    BARL;
    // s=0
    COMP(0, accA, xA0, xA1, xA2, xA3); AFLD(1, xB0, xB1, xB2, xB3);
    WWRITE(1); STAGE(2, KA); BARL;
    // s=1
    COMP(1, accA, xB0, xB1, xB2, xB3); AFLD(2, xA0, xA1, xA2, xA3);
    WWRITE(2); STAGE(3, KA); BARL;
    // s=2
    COMP(2, accA, xA0, xA1, xA2, xA3); AFLD(3, xB0, xB1, xB2, xB3);
    WWRITE(3); STAGE(4, KV); BARL;
    // s=3 (audio done)
    COMP(3, accA, xB0, xB1, xB2, xB3); AFLD(4, xA0, xA1, xA2, xA3);
    REDUCE(accA, ws + EXTA_OFF);
    WWRITE(4); STAGE(5, KV); BARL;
    // s=4
    COMP(4, accV, xA0, xA1, xA2, xA3); AFLD(5, xB0, xB1, xB2, xB3);
    WWRITE(5); BARL;
    // s=5
    COMP(5, accV, xB0, xB1, xB2, xB3);
    REDUCE(accV, ws + EXTV_OFF);

#undef STAGE
#undef CVT4
#undef WWRITE
#undef AFLD
#undef COMP
#undef BARL
#undef REDUCE
}

// ---------------- combine: ext + cpt + sigmoid dynamics ----------------
__global__ __launch_bounds__(256) void combine_kernel(
    const float* __restrict__ na_v, const float* __restrict__ na_a,
    const float* __restrict__ na_m, const float* __restrict__ ws,
    float* __restrict__ out)
{
    const int npq = NPOS >> 2;
    const int t = blockIdx.x * 256 + threadIdx.x;
    if (t >= BB * npq) return;
    const int b  = t / npq;
    const int p0 = (t - b * npq) << 2;

    float4 ev = *(const float4*)&ws[EXTV_OFF + (size_t)b * NPOS + p0];
    float4 ea = *(const float4*)&ws[EXTA_OFF + (size_t)b * NPOS + p0];
    const float* cpt = ws + CPT_OFF;
    float4 q0 = *(const float4*)&cpt[0 * NPOS + p0];
    float4 q1 = *(const float4*)&cpt[1 * NPOS + p0];
    float4 q2 = *(const float4*)&cpt[2 * NPOS + p0];
    float4 q3 = *(const float4*)&cpt[3 * NPOS + p0];
    float4 q4 = *(const float4*)&cpt[4 * NPOS + p0];
    float4 q5 = *(const float4*)&cpt[5 * NPOS + p0];
    float4 nv = *(const float4*)&na_v[p0];
    float4 na = *(const float4*)&na_a[p0];
    float4 nm = *(const float4*)&na_m[p0];

    float evs[4] = {ev.x, ev.y, ev.z, ev.w};
    float eas[4] = {ea.x, ea.y, ea.z, ea.w};
    float nbv[4] = {q0.x + q1.x, q0.y + q1.y, q0.z + q1.z, q0.w + q1.w};
    float nba[4] = {q2.x + q3.x, q2.y + q3.y, q2.z + q3.z, q2.w + q3.w};
    float nbm[4] = {q4.x + q5.x, q4.y + q5.y, q4.z + q5.z, q4.w + q5.w};
    float nvs[4] = {nv.x, nv.y, nv.z, nv.w};
    float nas[4] = {na.x, na.y, na.z, na.w};
    float nms[4] = {nm.x, nm.y, nm.z, nm.w};

    float4 o;
    float* os = (float*)&o;
    #pragma unroll
    for (int u = 0; u < 4; u++) {
        const float xv = (evs[u] + nbv[u] - 3.0f + nms[u]) * 0.3f;
        const float nav_new = nvs[u] * (2.f / 3.f) + (1.f / 3.f) / (1.f + __expf(-xv));
        const float xa = (eas[u] + nba[u] - 3.0f + nms[u]) * 0.3f;
        const float naa_new = nas[u] * (2.f / 3.f) + (1.f / 3.f) / (1.f + __expf(-xa));
        const float xm = (7.0f * nav_new + 3.0f * naa_new + nbm[u] - 3.0f) * 0.3f;
        os[u] = nms[u] * (2.f / 3.f) + (1.f / 3.f) / (1.f + __expf(-xm));
    }
    *(float4*)&out[(size_t)b * NPOS + p0] = o;
}

extern "C" void kernel_launch(void* const* d_in, const int* in_sizes, int n_in,
                              void* d_out, int out_size, void* d_ws, size_t ws_size,
                              hipStream_t stream) {
    const float* video = (const float*)d_in[0];
    const float* audio = (const float*)d_in[1];
    const float* rf_v  = (const float*)d_in[2];
    const float* rf_a  = (const float*)d_in[3];
    const float* na_v  = (const float*)d_in[4];
    const float* na_a  = (const float*)d_in[5];
    const float* na_m  = (const float*)d_in[6];
    float* ws  = (float*)d_ws;
    float* out = (float*)d_out;

    nbT_kernel<<<72, 256, 0, stream>>>(na_v, na_a, na_m, video, audio, ws);
    ext_mfma<<<576, 512, 0, stream>>>(rf_v, rf_a, ws);
    combine_kernel<<<(BB * NPOS / 4 + 255) / 256, 256, 0, stream>>>(
        na_v, na_a, na_m, ws, out);
}